// Round 6
// baseline (37.811 us; speedup 1.0000x reference)
//
#include <hip/hip_runtime.h>

#define NND 2000
#define KNB 16
#define CS 128
#define CZ 64
#define NE (NND*KNB)

typedef __attribute__((ext_vector_type(8))) short short8;
typedef __attribute__((ext_vector_type(4))) float f32x4;

__device__ __forceinline__ unsigned short f2bf(float f) {
  unsigned int u = __float_as_uint(f);
  u += 0x7fffu + ((u >> 16) & 1u);      // RNE round to bf16
  return (unsigned short)(u >> 16);
}

__device__ __forceinline__ float fexp2(float x) {
#if __has_builtin(__builtin_amdgcn_exp2f)
  return __builtin_amdgcn_exp2f(x);
#else
  return __expf(0.6931471805599453f * x);
#endif
}

// ---------------------------------------------------------------------------
// Precompute:
//   blocks [0,32): G-GEMM via MFMA. G1|G2 = nf @ w_gate (bf16), 16 rows/wave,
//                  b_gate folded into G1, log2e folded into both.
//   block 32: wave0 bias2 = b_out + ln_b@w_out; wave1 wdbF; wave2 wedF;
//             wave3 woF (bf16 MFMA B-fragments).
// ---------------------------------------------------------------------------
__global__ __launch_bounds__(256) void precompute_kernel(
    const float* __restrict__ nf,
    const float* __restrict__ w_gate, const float* __restrict__ b_gate,
    const float* __restrict__ ln_b, const float* __restrict__ w_out,
    const float* __restrict__ b_out,
    const float* __restrict__ w_db, const float* __restrict__ w_edge,
    const float* __restrict__ ln_g,
    float* __restrict__ g1, float* __restrict__ g2, float* __restrict__ bias2,
    unsigned short* __restrict__ wdbF, unsigned short* __restrict__ wedF,
    unsigned short* __restrict__ woF)
{
  const int p = threadIdx.x;
  const int w = p >> 6, l = p & 63, q = l >> 4, c = l & 15;
  const int b = blockIdx.x;
  const float LOG2E = 1.4426950408889634f;

  if (b < 32) {
    const int row0 = b*64 + 16*w;        // 16 node-rows per wave
    if (row0 >= NND) return;             // tail waves idle (no barriers here)
    // A-frags: nf row (row0+c), k = 32s+8q+t  (8 consecutive floats per s)
    short8 af[4];
    #pragma unroll
    for (int s = 0; s < 4; ++s) {
      const float* src = &nf[(row0 + c)*CS + 32*s + 8*q];
      const f32x4 x0 = *(const f32x4*)src;
      const f32x4 x1 = *(const f32x4*)(src + 4);
      short8 v;
      v[0]=(short)f2bf(x0[0]); v[1]=(short)f2bf(x0[1]);
      v[2]=(short)f2bf(x0[2]); v[3]=(short)f2bf(x0[3]);
      v[4]=(short)f2bf(x1[0]); v[5]=(short)f2bf(x1[1]);
      v[6]=(short)f2bf(x1[2]); v[7]=(short)f2bf(x1[3]);
      af[s] = v;
    }
    #pragma unroll
    for (int nt2 = 0; nt2 < 8; ++nt2) {  // 8 col-tiles: 0-3 -> G1, 4-7 -> G2
      const int colg = 16*(nt2 & 3) + c;
      const int rowoff = (nt2 < 4) ? 0 : CS;
      short8 bf[4];
      #pragma unroll
      for (int s = 0; s < 4; ++s) {
        short8 v;
        #pragma unroll
        for (int t = 0; t < 8; ++t)
          v[t] = (short)f2bf(w_gate[(rowoff + 32*s + 8*q + t)*CZ + colg]);
        bf[s] = v;
      }
      f32x4 acc = {};
      #pragma unroll
      for (int s = 0; s < 4; ++s)
        acc = __builtin_amdgcn_mfma_f32_16x16x32_bf16(af[s], bf[s], acc, 0, 0, 0);
      float* dst = (nt2 < 4) ? g1 : g2;
      const float bias = (nt2 < 4) ? b_gate[colg] : 0.f;
      #pragma unroll
      for (int r = 0; r < 4; ++r)
        dst[(row0 + 4*q + r)*CZ + colg] = (acc[r] + bias) * LOG2E;
    }
  } else {
    const int lane = l, wv = w;
    if (wv == 0) {
      float a = b_out[lane];
      #pragma unroll
      for (int cc = 0; cc < CZ; ++cc)
        a = fmaf(ln_b[cc], w_out[cc*CZ + lane], a);
      bias2[lane] = a;
    } else if (wv == 1) {
      for (int e = lane; e < 4096; e += 64) {
        const int entry = e >> 3, t = e & 7;
        const int l2 = entry & 63, sn = entry >> 6;
        const int s = sn >> 2, nt = sn & 3;
        const int q2 = l2 >> 4, c2 = l2 & 15;
        wdbF[e] = f2bf(w_db[(32*s + 8*q2 + t)*CZ + 16*nt + c2]);
      }
    } else if (wv == 2) {
      for (int e = lane; e < 4096; e += 64) {
        const int entry = e >> 3, t = e & 7;
        const int p2 = entry & 255, s = entry >> 8;
        const int q2 = (p2 >> 4) & 3, c2 = p2 & 15;
        wedF[e] = f2bf(w_edge[(32*s + 8*q2 + t)*CZ + 16*(p2 >> 6) + c2]);
      }
    } else {
      for (int e = lane; e < 4096; e += 64) {
        const int entry = e >> 3, t = e & 7;
        const int p2 = entry & 255, s = entry >> 8;
        const int q2 = (p2 >> 4) & 3, c2 = p2 & 15;
        const int k = 32*s + 8*q2 + t;
        woF[e] = f2bf(w_out[k*CZ + 16*(p2 >> 6) + c2] * ln_g[k]);
      }
    }
  }
}

// ---------------------------------------------------------------------------
// Fused main kernel: one block (4 waves) per node, ONE barrier.
//   kf C-frags computed redundantly per wave (lands in exactly the lanes the
//   gate phase needs); ef A-frags + G1/G2 read direct from global; biases
//   folded into MFMA C-init. Only the xhat transpose needs LDS.
// ---------------------------------------------------------------------------
__global__ __launch_bounds__(256, 4) void fused_main_kernel(
    const float* __restrict__ trans, const int* __restrict__ eidx,
    const float* __restrict__ g1, const float* __restrict__ g2,
    const float* __restrict__ ef, const float* __restrict__ b_edge,
    const float* __restrict__ b_db, const float* __restrict__ bias2,
    const unsigned short* __restrict__ wdbF,
    const unsigned short* __restrict__ wedF,
    const unsigned short* __restrict__ woF,
    float* __restrict__ out)
{
  __shared__ unsigned short xh[KNB][72];     // xhat bf16 (transpose for MFMA2)

  const int n = blockIdx.x;
  const int p = threadIdx.x;
  const int w = p >> 6, l = p & 63, q = l >> 4, c = l & 15;
  const int base = n*KNB;

  // ---- independent front-loaded traffic --------------------------------
  const int e_c = eidx[base + c];            // node of edge i=c
  int e_j[4], e_q[4];
  #pragma unroll
  for (int m = 0; m < 4; ++m) e_j[m] = eidx[base + 4*w + m];
  #pragma unroll
  for (int r = 0; r < 4; ++r) e_q[r] = eidx[base + 4*q + r];

  const float tc0 = trans[e_c*3+0], tc1 = trans[e_c*3+1], tc2 = trans[e_c*3+2];
  float tj[4][3];
  #pragma unroll
  for (int m = 0; m < 4; ++m) {
    tj[m][0] = trans[e_j[m]*3+0];
    tj[m][1] = trans[e_j[m]*3+1];
    tj[m][2] = trans[e_j[m]*3+2];
  }

  // ef A-frags direct from global: row (edge i=c), k = 32s+8q+t
  short8 afe[2];
  #pragma unroll
  for (int s = 0; s < 2; ++s) {
    const float* src = &ef[(base + c)*CZ + 32*s + 8*q];
    const f32x4 x0 = *(const f32x4*)src;
    const f32x4 x1 = *(const f32x4*)(src + 4);
    short8 v;
    v[0]=(short)f2bf(x0[0]); v[1]=(short)f2bf(x0[1]);
    v[2]=(short)f2bf(x0[2]); v[3]=(short)f2bf(x0[3]);
    v[4]=(short)f2bf(x1[0]); v[5]=(short)f2bf(x1[1]);
    v[6]=(short)f2bf(x1[2]); v[7]=(short)f2bf(x1[3]);
    afe[s] = v;
  }

  // ---- kf = ef @ w_edge + b_edge, all 4 col-blocks per wave ------------
  f32x4 kfc[4];
  #pragma unroll
  for (int cb = 0; cb < 4; ++cb) {
    const float be = b_edge[16*cb + c];
    kfc[cb] = (f32x4){be, be, be, be};
  }
  #pragma unroll
  for (int s = 0; s < 2; ++s) {
    #pragma unroll
    for (int cb = 0; cb < 4; ++cb) {
      const short8 wed = *(const short8*)&wedF[(s*256 + cb*64 + l)*8];
      kfc[cb] = __builtin_amdgcn_mfma_f32_16x16x32_bf16(afe[s], wed, kfc[cb], 0, 0, 0);
    }
  }

  // ---- distances + rbf A-frags (pair i=c, j=4w+m) ----------------------
  const float STEP = 1.2201878439258035f;    // (20/63)*3.2*sqrt(log2e)
  float dsc[4];
  #pragma unroll
  for (int m = 0; m < 4; ++m) {
    const float dx = tc0 - tj[m][0] + 1e-8f;
    const float dy = tc1 - tj[m][1] + 1e-8f;
    const float dz = tc2 - tj[m][2] + 1e-8f;
    dsc[m] = sqrtf(fmaf(dx,dx, fmaf(dy,dy, dz*dz))) * 3.8435917081166394f;
  }
  const float qoff = (float)(8*q) * STEP;
  short8 af[2][4];
  #pragma unroll
  for (int s = 0; s < 2; ++s) {
    const float soff = qoff + (float)(32*s) * STEP;
    #pragma unroll
    for (int m = 0; m < 4; ++m) {
      const float bse = dsc[m] - soff;
      short8 v;
      #pragma unroll
      for (int t = 0; t < 8; ++t) {
        const float u = fmaf(-STEP, (float)t, bse);
        v[t] = (short)f2bf(fexp2(-u*u));
      }
      af[s][m] = v;
    }
  }

  // ---- per-nt: MFMA1 (C-init = b_db) + gate + i-reduce -----------------
  short8 bcur[2];
  #pragma unroll
  for (int s = 0; s < 2; ++s)
    bcur[s] = *(const short8*)&wdbF[(s*4*64 + l)*8];

  float upd[4][4];   // [m][nt]
  #pragma unroll
  for (int nt = 0; nt < 4; ++nt) {
    short8 bnext[2];
    if (nt < 3) {
      #pragma unroll
      for (int s = 0; s < 2; ++s)
        bnext[s] = *(const short8*)&wdbF[((s*4 + nt+1)*64 + l)*8];
    }
    // gate operand gathers (64B-coalesced per quarter-wave, L2-resident)
    float g1v[4], g2v[4];
    #pragma unroll
    for (int r = 0; r < 4; ++r) g1v[r] = g1[e_q[r]*CZ + 16*nt + c];
    #pragma unroll
    for (int m = 0; m < 4; ++m) g2v[m] = g2[e_j[m]*CZ + 16*nt + c];

    const float bdbn = b_db[16*nt + c];
    f32x4 accD[4];
    #pragma unroll
    for (int m = 0; m < 4; ++m) accD[m] = (f32x4){bdbn, bdbn, bdbn, bdbn};
    #pragma unroll
    for (int s = 0; s < 2; ++s)
      #pragma unroll
      for (int m = 0; m < 4; ++m)
        accD[m] = __builtin_amdgcn_mfma_f32_16x16x32_bf16(af[s][m], bcur[s], accD[m], 0, 0, 0);

    #pragma unroll
    for (int m = 0; m < 4; ++m) {
      float ss = 0.f;
      #pragma unroll
      for (int r = 0; r < 4; ++r) {
        const float gate = __builtin_amdgcn_rcpf(1.0f + fexp2(-(g1v[r] + g2v[m])));
        ss = fmaf(gate * accD[m][r], kfc[nt][r], ss);
      }
      ss += __shfl_xor(ss, 16);
      ss += __shfl_xor(ss, 32);
      upd[m][nt] = ss;
    }
    if (nt < 3) { bcur[0] = bnext[0]; bcur[1] = bnext[1]; }
  }

  // proj B-frags (hide latency under LN)
  short8 wb[2];
  #pragma unroll
  for (int s = 0; s < 2; ++s)
    wb[s] = *(const short8*)&woF[(s*256 + p)*8];

  // ---- LayerNorm: group q owns row j = 4w+q ----------------------------
  {
    float v[4];
    #pragma unroll
    for (int nt = 0; nt < 4; ++nt)
      v[nt] = (q == 0) ? upd[0][nt] : (q == 1) ? upd[1][nt]
            : (q == 2) ? upd[2][nt] : upd[3][nt];
    float s1 = (v[0] + v[1]) + (v[2] + v[3]);
    float s2 = fmaf(v[0],v[0], fmaf(v[1],v[1], fmaf(v[2],v[2], v[3]*v[3])));
    #pragma unroll
    for (int mk = 1; mk <= 8; mk <<= 1) {
      s1 += __shfl_xor(s1, mk);
      s2 += __shfl_xor(s2, mk);
    }
    const float mean = s1 * 0.015625f;
    const float var  = fmaf(s2, 0.015625f, -mean*mean);
    const float rstd = rsqrtf(var + 1e-5f);
    #pragma unroll
    for (int nt = 0; nt < 4; ++nt)
      xh[4*w + q][16*nt + c] = f2bf((v[nt] - mean) * rstd);
  }
  __syncthreads();   // the only barrier: xh transpose for MFMA2

  // ---- MFMA2: out = xhat @ (ln_g*w_out) + bias2 ------------------------
  f32x4 acc2 = {};
  #pragma unroll
  for (int s = 0; s < 2; ++s) {
    const short8 a2f = *(const short8*)&xh[c][q*8 + 32*s];
    acc2 = __builtin_amdgcn_mfma_f32_16x16x32_bf16(a2f, wb[s], acc2, 0, 0, 0);
  }
  const float bo = bias2[16*w + c];
  #pragma unroll
  for (int r = 0; r < 4; ++r)
    out[(base + 4*q + r)*CZ + 16*w + c] = acc2[r] + bo;
}

extern "C" void kernel_launch(void* const* d_in, const int* in_sizes, int n_in,
                              void* d_out, int out_size, void* d_ws, size_t ws_size,
                              hipStream_t stream)
{
  const float* nf     = (const float*)d_in[0];
  const float* trans  = (const float*)d_in[1];
  const float* ef     = (const float*)d_in[2];
  const int*   eidx   = (const int*)d_in[3];
  const float* w_gate = (const float*)d_in[4];
  const float* b_gate = (const float*)d_in[5];
  const float* w_db   = (const float*)d_in[6];
  const float* b_db   = (const float*)d_in[7];
  const float* w_edge = (const float*)d_in[8];
  const float* b_edge = (const float*)d_in[9];
  const float* ln_g   = (const float*)d_in[10];
  const float* ln_b   = (const float*)d_in[11];
  const float* w_out  = (const float*)d_in[12];
  const float* b_out  = (const float*)d_in[13];
  float* out = (float*)d_out;

  float* g1    = (float*)d_ws;           // [2000][64]
  float* g2    = g1 + NND*CZ;            // [2000][64]
  float* bias2 = g2 + NND*CZ;            // [64]
  unsigned short* wdbF = (unsigned short*)(bias2 + CZ);
  unsigned short* wedF = wdbF + 4096;
  unsigned short* woF  = wedF + 4096;

  precompute_kernel<<<33, 256, 0, stream>>>(
      nf, w_gate, b_gate, ln_b, w_out, b_out, w_db, w_edge, ln_g,
      g1, g2, bias2, wdbF, wedF, woF);
  fused_main_kernel<<<NND, 256, 0, stream>>>(
      trans, eidx, g1, g2, ef, b_edge, b_db, bias2,
      wdbF, wedF, woF, out);
}

// Round 8
// 37.591 us; speedup vs baseline: 1.0059x; 1.0059x over previous
//
#include <hip/hip_runtime.h>
#include <hip/hip_bf16.h>

#define NND 2000
#define KNB 16
#define CS 128
#define CZ 64
#define NE (NND*KNB)

typedef __attribute__((ext_vector_type(8))) short short8;
typedef __attribute__((ext_vector_type(4))) float f32x4;
typedef __attribute__((ext_vector_type(4))) unsigned int uint4v;

// hardware bf16 convert (compiler emits v_cvt_pk_bf16_f32; RNE)
__device__ __forceinline__ unsigned int pk2(float a, float b) {
  __hip_bfloat162 h = __float22bfloat162_rn(make_float2(a, b));
  unsigned int u;
  __builtin_memcpy(&u, &h, 4);
  return u;
}
__device__ __forceinline__ unsigned short bfc(float f) {
  __hip_bfloat16 h = __float2bfloat16(f);
  unsigned short u;
  __builtin_memcpy(&u, &h, 2);
  return u;
}

__device__ __forceinline__ float fexp2(float x) {
#if __has_builtin(__builtin_amdgcn_exp2f)
  return __builtin_amdgcn_exp2f(x);
#else
  return __expf(0.6931471805599453f * x);
#endif
}

// ---------------------------------------------------------------------------
// Precompute:
//   blocks [0,500): per-node gate logits G1/G2 (ILP-4), b_gate folded in G1,
//                   log2e folded into both (gate uses exp2).
//   blocks [500,625): ef -> bf16 copy (efB), coalesced streaming.
//   block 625: wave0 bias2; wave1 wdbF; wave2 wedF; wave3 woF (bf16 frags).
// ---------------------------------------------------------------------------
__global__ __launch_bounds__(256) void precompute_kernel(
    const float* __restrict__ nf, const float* __restrict__ ef,
    const float* __restrict__ w_gate, const float* __restrict__ b_gate,
    const float* __restrict__ ln_b, const float* __restrict__ w_out,
    const float* __restrict__ b_out,
    const float* __restrict__ w_db, const float* __restrict__ w_edge,
    const float* __restrict__ ln_g,
    float* __restrict__ g1, float* __restrict__ g2, float* __restrict__ bias2,
    unsigned short* __restrict__ wdbF, unsigned short* __restrict__ wedF,
    unsigned short* __restrict__ woF, unsigned short* __restrict__ efB)
{
  const int p = threadIdx.x;
  const int lane = p & 63;
  const int wv   = p >> 6;
  const int b    = blockIdx.x;
  if (b < NND/4) {
    const int v = b*4 + wv;
    const float* nrow = nf + v*CS;
    float a10=0.f,a11=0.f,a12=0.f,a13=0.f;
    float a20=0.f,a21=0.f,a22=0.f,a23=0.f;
    #pragma unroll
    for (int cc = 0; cc < CS; cc += 4) {
      const f32x4 x = *(const f32x4*)&nrow[cc];
      a10 = fmaf(x[0], w_gate[(cc+0)*CZ + lane], a10);
      a11 = fmaf(x[1], w_gate[(cc+1)*CZ + lane], a11);
      a12 = fmaf(x[2], w_gate[(cc+2)*CZ + lane], a12);
      a13 = fmaf(x[3], w_gate[(cc+3)*CZ + lane], a13);
      a20 = fmaf(x[0], w_gate[(CS+cc+0)*CZ + lane], a20);
      a21 = fmaf(x[1], w_gate[(CS+cc+1)*CZ + lane], a21);
      a22 = fmaf(x[2], w_gate[(CS+cc+2)*CZ + lane], a22);
      a23 = fmaf(x[3], w_gate[(CS+cc+3)*CZ + lane], a23);
    }
    const float a1 = b_gate[lane] + ((a10+a11)+(a12+a13));
    const float a2 = (a20+a21)+(a22+a23);
    g1[v*CZ + lane] = a1 * 1.4426950408889634f;
    g2[v*CZ + lane] = a2 * 1.4426950408889634f;
  } else if (b < NND/4 + 125) {
    // ef -> bf16: block owns 256 rows = 16384 elems, 8 iterations
    const int bb = b - NND/4;
    const int base = bb * 16384;
    #pragma unroll
    for (int it = 0; it < 8; ++it) {
      const int off = base + it*2048 + p*8;
      const f32x4 x0 = *(const f32x4*)&ef[off];
      const f32x4 x1 = *(const f32x4*)&ef[off + 4];
      uint4v u;
      u[0] = pk2(x0[0], x0[1]);
      u[1] = pk2(x0[2], x0[3]);
      u[2] = pk2(x1[0], x1[1]);
      u[3] = pk2(x1[2], x1[3]);
      *(uint4v*)&efB[off] = u;
    }
  } else {
    if (wv == 0) {
      float a = b_out[lane];
      #pragma unroll
      for (int cc = 0; cc < CZ; ++cc)
        a = fmaf(ln_b[cc], w_out[cc*CZ + lane], a);
      bias2[lane] = a;
    } else if (wv == 1) {
      for (int e = lane; e < 4096; e += 64) {
        const int entry = e >> 3, t = e & 7;
        const int l2 = entry & 63, sn = entry >> 6;
        const int s = sn >> 2, nt = sn & 3;
        const int q2 = l2 >> 4, c2 = l2 & 15;
        wdbF[e] = bfc(w_db[(32*s + 8*q2 + t)*CZ + 16*nt + c2]);
      }
    } else if (wv == 2) {
      for (int e = lane; e < 4096; e += 64) {
        const int entry = e >> 3, t = e & 7;
        const int p2 = entry & 255, s = entry >> 8;
        const int q2 = (p2 >> 4) & 3, c2 = p2 & 15;
        wedF[e] = bfc(w_edge[(32*s + 8*q2 + t)*CZ + 16*(p2 >> 6) + c2]);
      }
    } else {
      for (int e = lane; e < 4096; e += 64) {
        const int entry = e >> 3, t = e & 7;
        const int p2 = entry & 255, s = entry >> 8;
        const int q2 = (p2 >> 4) & 3, c2 = p2 & 15;
        const int k = 32*s + 8*q2 + t;
        woF[e] = bfc(w_out[k*CZ + 16*(p2 >> 6) + c2] * ln_g[k]);
      }
    }
  }
}

// ---------------------------------------------------------------------------
// Fused main kernel: one block (4 waves) per node, TWO barriers.
//   ef A-frags direct from efB (bf16); MFMA0 pre-barrier; G rows staged to
//   LDS from front-loaded registers; all cvts via v_cvt_pk_bf16_f32.
// ---------------------------------------------------------------------------
__global__ __launch_bounds__(256, 4) void fused_main_kernel(
    const float* __restrict__ trans, const int* __restrict__ eidx,
    const float* __restrict__ g1, const float* __restrict__ g2,
    const unsigned short* __restrict__ efB, const float* __restrict__ b_edge,
    const float* __restrict__ b_db, const float* __restrict__ bias2,
    const unsigned short* __restrict__ wdbF,
    const unsigned short* __restrict__ wedF,
    const unsigned short* __restrict__ woF,
    float* __restrict__ out)
{
  __shared__ float G1l[KNB][68];
  __shared__ float G2l[KNB][68];
  __shared__ float kfl[KNB][68];
  __shared__ unsigned short xh[KNB][72];     // xhat bf16 (transpose for MFMA2)

  const int n = blockIdx.x;
  const int p = threadIdx.x;
  const int w = p >> 6, l = p & 63, q = l >> 4, c = l & 15;
  const int base = n*KNB;
  const int r16 = p >> 4, c4 = (p & 15) * 4;

  // ---- front-loaded global traffic --------------------------------------
  const int sr = eidx[base + r16];           // G-row gather index
  const int sc = eidx[base + c];             // t_i index
  int sj[4];
  #pragma unroll
  for (int m = 0; m < 4; ++m) sj[m] = eidx[base + 4*w + m];

  const f32x4 g1row = *(const f32x4*)&g1[sr*CZ + c4];
  const f32x4 g2row = *(const f32x4*)&g2[sr*CZ + c4];

  const float tc0 = trans[sc*3+0], tc1 = trans[sc*3+1], tc2 = trans[sc*3+2];
  float tj[4][3];
  #pragma unroll
  for (int m = 0; m < 4; ++m) {
    tj[m][0] = trans[sj[m]*3+0];
    tj[m][1] = trans[sj[m]*3+1];
    tj[m][2] = trans[sj[m]*3+2];
  }

  // ef A-frags: bf16 direct (row = edge i=c, k = 32s+8q+t)
  short8 afe[2];
  #pragma unroll
  for (int s = 0; s < 2; ++s)
    afe[s] = *(const short8*)&efB[(base + c)*CZ + 32*s + 8*q];

  short8 wed[2];
  #pragma unroll
  for (int s = 0; s < 2; ++s)
    wed[s] = *(const short8*)&wedF[(s*256 + p)*8];
  short8 bcur[2];
  #pragma unroll
  for (int s = 0; s < 2; ++s)
    bcur[s] = *(const short8*)&wdbF[(s*4*64 + l)*8];

  const float be = b_edge[16*w + c];
  const float bo = bias2[16*w + c];
  float bdb[4];
  #pragma unroll
  for (int nt = 0; nt < 4; ++nt) bdb[nt] = b_db[16*nt + c];

  // ---- MFMA0 (no LDS deps): kf tile; wave w owns cols 16w..16w+15 -------
  {
    f32x4 ak = {};
    #pragma unroll
    for (int s = 0; s < 2; ++s)
      ak = __builtin_amdgcn_mfma_f32_16x16x32_bf16(afe[s], wed[s], ak, 0, 0, 0);
    #pragma unroll
    for (int r = 0; r < 4; ++r)
      kfl[4*q + r][16*w + c] = ak[r] + be;
  }
  { // stage G rows (register -> LDS)
    *(f32x4*)&G1l[r16][c4] = g1row;
    *(f32x4*)&G2l[r16][c4] = g2row;
  }

  // ---- distances + rbf A-frags (pair i=c, j=4w+m), packed cvt -----------
  const float STEP = 1.2201878439258035f;    // (20/63)*3.2*sqrt(log2e)
  float dsc[4];
  #pragma unroll
  for (int m = 0; m < 4; ++m) {
    const float dx = tc0 - tj[m][0] + 1e-8f;
    const float dy = tc1 - tj[m][1] + 1e-8f;
    const float dz = tc2 - tj[m][2] + 1e-8f;
    dsc[m] = sqrtf(fmaf(dx,dx, fmaf(dy,dy, dz*dz))) * 3.8435917081166394f;
  }
  const float qoff = (float)(8*q) * STEP;
  short8 af[2][4];
  #pragma unroll
  for (int s = 0; s < 2; ++s) {
    const float soff = qoff + (float)(32*s) * STEP;
    #pragma unroll
    for (int m = 0; m < 4; ++m) {
      const float bse = dsc[m] - soff;
      uint4v u;
      #pragma unroll
      for (int t = 0; t < 4; ++t) {
        const float ua = fmaf(-STEP, (float)(2*t),   bse);
        const float ub = fmaf(-STEP, (float)(2*t+1), bse);
        u[t] = pk2(fexp2(-ua*ua), fexp2(-ub*ub));
      }
      short8 v;
      __builtin_memcpy(&v, &u, 16);
      af[s][m] = v;
    }
  }
  __syncthreads();   // b1: kfl + G1l/G2l visible

  // ---- per-nt: MFMA1 (C-init = b_db) + gate + i-reduce ------------------
  float upd[4][4];   // [m][nt]
  #pragma unroll
  for (int nt = 0; nt < 4; ++nt) {
    short8 bnext[2];
    if (nt < 3) {
      #pragma unroll
      for (int s = 0; s < 2; ++s)
        bnext[s] = *(const short8*)&wdbF[((s*4 + nt+1)*64 + l)*8];
    }
    float g1v[4], kfv[4];
    #pragma unroll
    for (int r = 0; r < 4; ++r) {
      g1v[r] = G1l[4*q + r][16*nt + c];
      kfv[r] = kfl[4*q + r][16*nt + c];
    }
    const float bdbn = bdb[nt];
    f32x4 accD[4];
    #pragma unroll
    for (int m = 0; m < 4; ++m) accD[m] = (f32x4){bdbn, bdbn, bdbn, bdbn};
    #pragma unroll
    for (int s = 0; s < 2; ++s)
      #pragma unroll
      for (int m = 0; m < 4; ++m)
        accD[m] = __builtin_amdgcn_mfma_f32_16x16x32_bf16(af[s][m], bcur[s], accD[m], 0, 0, 0);

    #pragma unroll
    for (int m = 0; m < 4; ++m) {
      const float g2vm = G2l[4*w + m][16*nt + c];
      float ss = 0.f;
      #pragma unroll
      for (int r = 0; r < 4; ++r) {
        const float gate = __builtin_amdgcn_rcpf(1.0f + fexp2(-(g1v[r] + g2vm)));
        ss = fmaf(gate * accD[m][r], kfv[r], ss);
      }
      ss += __shfl_xor(ss, 16);
      ss += __shfl_xor(ss, 32);
      upd[m][nt] = ss;
    }
    if (nt < 3) { bcur[0] = bnext[0]; bcur[1] = bnext[1]; }
  }

  // proj B-frags (hide under LN)
  short8 wb[2];
  #pragma unroll
  for (int s = 0; s < 2; ++s)
    wb[s] = *(const short8*)&woF[(s*256 + p)*8];

  // ---- LayerNorm: group q owns row j = 4w+q -----------------------------
  {
    float v[4];
    #pragma unroll
    for (int nt = 0; nt < 4; ++nt)
      v[nt] = (q == 0) ? upd[0][nt] : (q == 1) ? upd[1][nt]
            : (q == 2) ? upd[2][nt] : upd[3][nt];
    float s1 = (v[0] + v[1]) + (v[2] + v[3]);
    float s2 = fmaf(v[0],v[0], fmaf(v[1],v[1], fmaf(v[2],v[2], v[3]*v[3])));
    #pragma unroll
    for (int mk = 1; mk <= 8; mk <<= 1) {
      s1 += __shfl_xor(s1, mk);
      s2 += __shfl_xor(s2, mk);
    }
    const float mean = s1 * 0.015625f;
    const float var  = fmaf(s2, 0.015625f, -mean*mean);
    const float rstd = rsqrtf(var + 1e-5f);
    #pragma unroll
    for (int nt = 0; nt < 4; ++nt)
      xh[4*w + q][16*nt + c] = bfc((v[nt] - mean) * rstd);
  }
  __syncthreads();   // b2: xh visible

  // ---- MFMA2: out = xhat @ (ln_g*w_out) + bias2 -------------------------
  f32x4 acc2 = {};
  #pragma unroll
  for (int s = 0; s < 2; ++s) {
    const short8 a2f = *(const short8*)&xh[c][q*8 + 32*s];
    acc2 = __builtin_amdgcn_mfma_f32_16x16x32_bf16(a2f, wb[s], acc2, 0, 0, 0);
  }
  #pragma unroll
  for (int r = 0; r < 4; ++r)
    out[(base + 4*q + r)*CZ + 16*w + c] = acc2[r] + bo;
}

extern "C" void kernel_launch(void* const* d_in, const int* in_sizes, int n_in,
                              void* d_out, int out_size, void* d_ws, size_t ws_size,
                              hipStream_t stream)
{
  const float* nf     = (const float*)d_in[0];
  const float* trans  = (const float*)d_in[1];
  const float* ef     = (const float*)d_in[2];
  const int*   eidx   = (const int*)d_in[3];
  const float* w_gate = (const float*)d_in[4];
  const float* b_gate = (const float*)d_in[5];
  const float* w_db   = (const float*)d_in[6];
  const float* b_db   = (const float*)d_in[7];
  const float* w_edge = (const float*)d_in[8];
  const float* b_edge = (const float*)d_in[9];
  const float* ln_g   = (const float*)d_in[10];
  const float* ln_b   = (const float*)d_in[11];
  const float* w_out  = (const float*)d_in[12];
  const float* b_out  = (const float*)d_in[13];
  float* out = (float*)d_out;

  float* g1    = (float*)d_ws;                            // [2000][64] f32
  float* g2    = g1 + NND*CZ;                             // [2000][64] f32
  float* bias2 = g2 + NND*CZ;                             // [64] f32
  unsigned short* wdbF = (unsigned short*)(bias2 + CZ);   // 4096 bf16
  unsigned short* wedF = wdbF + 4096;                     // 4096 bf16
  unsigned short* woF  = wedF + 4096;                     // 4096 bf16
  unsigned short* efB  = woF  + 4096;                     // [32000][64] bf16

  precompute_kernel<<<NND/4 + 125 + 1, 256, 0, stream>>>(
      nf, ef, w_gate, b_gate, ln_b, w_out, b_out, w_db, w_edge, ln_g,
      g1, g2, bias2, wdbF, wedF, woF, efB);
  fused_main_kernel<<<NND, 256, 0, stream>>>(
      trans, eidx, g1, g2, efB, b_edge, b_db, bias2,
      wdbF, wedF, woF, out);
}